// Round 8
// baseline (155.794 us; speedup 1.0000x reference)
//
#include <hip/hip_runtime.h>
#include <hip/hip_bf16.h>
#include <cstdint>
#include <cstddef>

// Problem constants (fixed by setup_inputs)
#define IN_F   512
#define OUT_F  512
#define KBASIS 8
#define BATCH  8192
#define KDIM   (IN_F * KBASIS)   // 4096

// GEMM tiling: 512 blocks (2/CU), 256 threads (4 waves = 2 N-cols x 2 K-halves)
#define BM 64
#define BN 128
#define BKS 64                    // kdim per K-step = 8 input features
#define NSTEPS (KDIM / BKS)       // 64
#define NTHREADS 256

typedef __attribute__((ext_vector_type(8))) short  short8;   // bf16x8 MFMA frag
typedef __attribute__((ext_vector_type(4))) float  f32x4;
typedef __attribute__((ext_vector_type(2))) float  f32x2;
typedef __attribute__((ext_vector_type(4))) unsigned int u32x4;

static __device__ __forceinline__ unsigned short f2bf16(float f) {
    union { float f; unsigned u; } v; v.f = f;
    unsigned u = v.u;
    return (unsigned short)((u + 0x7FFFu + ((u >> 16) & 1u)) >> 16);  // RNE
}

static __device__ __forceinline__ unsigned cvtpk(float lo, float hi) {
    unsigned r;
    asm("v_cvt_pk_bf16_f32 %0, %1, %2" : "=v"(r) : "v"(lo), "v"(hi));
    return r;
}

// ---------------- prep 1: per-feature table, interleaved float4 ----------
// basis_{i,k}(x) = rcp(1 + e_k), e_k = exp2(KA_i*x + KB0_i) * RR_i^k
__global__ void prep_tabs(const float* __restrict__ raw_alpha,
                          const float* __restrict__ beta,
                          const float* __restrict__ centers,
                          const float* __restrict__ slopes,
                          float4* __restrict__ Tab) {
    int i = blockIdx.x * blockDim.x + threadIdx.x;
    if (i >= IN_F) return;
    float ra = raw_alpha[i];
    float sp = (ra > 20.f) ? ra : log1pf(expf(ra));   // softplus
    float alpha = sp + 1e-6f;
    const float NEG2LOG2E = -2.8853900817779268f;     // -2*log2(e)
    float s0 = slopes[i * KBASIS + 0], c0 = centers[i * KBASIS + 0];
    float s1 = slopes[i * KBASIS + 1], c1 = centers[i * KBASIS + 1];
    float kb0 = NEG2LOG2E * s0 * (beta[i] - c0);
    float kb1 = NEG2LOG2E * s1 * (beta[i] - c1);
    float4 t;
    t.x = NEG2LOG2E * s0 * alpha;   // KA
    t.y = kb0;                      // KB0
    t.z = exp2f(kb1 - kb0);         // RR
    t.w = 0.f;
    Tab[i] = t;
}

// ---------------- prep 2: coeffs fp32 -> bf16 (layout preserved) ----------
__global__ void prep_wb(const float* __restrict__ w,
                        unsigned short* __restrict__ wb, int n4) {
    int idx = blockIdx.x * blockDim.x + threadIdx.x;
    if (idx >= n4) return;
    float4 v = *(const float4*)(w + (size_t)idx * 4);
    ushort4 r;
    r.x = f2bf16(v.x); r.y = f2bf16(v.y); r.z = f2bf16(v.z); r.w = f2bf16(v.w);
    *(ushort4*)(wb + (size_t)idx * 4) = r;
}

// ---------------- fused basis-expansion GEMM ----------------
// B-frags global->reg with 1-step register double-buffer (E/O sets).
// A computed on the fly into a 16 KB LDS double buffer.
// x/tab for A(t+1) loaded at body top, consumed after MFMA (latency hidden).
// Plain __syncthreads() everywhere (full compiler fence) - no inline-asm sync.
__global__ __launch_bounds__(NTHREADS, 2)
void fused_tanh_gemm(const float* __restrict__ x,
                     const unsigned short* __restrict__ Wb,   // bf16 bits
                     const float4* __restrict__ Tab,
                     float* __restrict__ out) {
    __shared__ __align__(16) char smem[32 * 1024];
    unsigned short* As0 = (unsigned short*)smem;          // [64][64] bf16, 8 KB
    unsigned short* As1 = As0 + 64 * 64;
    float* red = (float*)smem;                            // epilogue alias [64][128]

    const int tid  = threadIdx.x;
    const int wid  = tid >> 6;
    const int lane = tid & 63;

    // 512 blocks: xcd-chunked so 64 blocks/XCD share the Wb panels
    const int bid = blockIdx.x;
    const int xcd = bid & 7;
    const int rix = bid >> 3;              // 0..63
    const int bn0 = (rix >> 4) * BN;       // 4 N-strips
    const int bm0 = (xcd * 16 + (rix & 15)) * BM;   // 128 M-strips

    // wave roles
    const int wc = wid & 1;                // N column 0..1
    const int ks = wid >> 1;               // K half 0..1
    const int fr = lane & 15;
    const int fq = lane >> 4;              // 0..3

    // A staging coords: thread covers 2 features of one row
    const int arow = tid >> 2;             // 0..63
    const int c0   = (tid & 3) * 2;        // feature-chunks c0, c0+1 (of 8/step)
    const float*  xptr = x + (size_t)(bm0 + arow) * IN_F + c0;
    const float4* tptr = Tab + c0;

    // A-write offsets (elements), XOR-swizzled chunks
    const int aw0 = arow * 64 + ((c0    ) ^ (arow & 7)) * 8;
    const int aw1 = arow * 64 + ((c0 + 1) ^ (arow & 7)) * 8;
    // A-read offset (elements): row fr (+mi*16), swizzled chunk
    const int sidx  = (ks * 4 + fq) ^ (fr & 7);
    const int laneA = fr * 64 + sidx * 8;

    // B-frag global base pointers (per ni), advance +64 elems per step
    const unsigned short* bq0 = Wb + (size_t)(bn0 + wc * 64 + 0 * 16 + fr) * KDIM + ks * 32 + fq * 8;
    const unsigned short* bq1 = bq0 + 16 * KDIM;
    const unsigned short* bq2 = bq0 + 32 * KDIM;
    const unsigned short* bq3 = bq0 + 48 * KDIM;

    // ---- stageA: build 2 feature-chunks of A(t+1) into bufWr ----
    auto stageA = [&](unsigned short* bufWr, f32x2 xv, f32x4 t0, f32x4 t1) {
        float e0 = __builtin_amdgcn_exp2f(t0[0] * xv[0] + t0[1]);
        float r0 = t0[2];
        float a0 = __builtin_amdgcn_rcpf(1.0f + e0); e0 *= r0;
        float a1 = __builtin_amdgcn_rcpf(1.0f + e0); e0 *= r0;
        float a2 = __builtin_amdgcn_rcpf(1.0f + e0); e0 *= r0;
        float a3 = __builtin_amdgcn_rcpf(1.0f + e0); e0 *= r0;
        float a4 = __builtin_amdgcn_rcpf(1.0f + e0); e0 *= r0;
        float a5 = __builtin_amdgcn_rcpf(1.0f + e0); e0 *= r0;
        float a6 = __builtin_amdgcn_rcpf(1.0f + e0); e0 *= r0;
        float a7 = __builtin_amdgcn_rcpf(1.0f + e0);
        u32x4 p0;
        p0[0] = cvtpk(a0, a1); p0[1] = cvtpk(a2, a3);
        p0[2] = cvtpk(a4, a5); p0[3] = cvtpk(a6, a7);
        *(u32x4*)(bufWr + aw0) = p0;

        float e1 = __builtin_amdgcn_exp2f(t1[0] * xv[1] + t1[1]);
        float r1 = t1[2];
        float b0 = __builtin_amdgcn_rcpf(1.0f + e1); e1 *= r1;
        float b1 = __builtin_amdgcn_rcpf(1.0f + e1); e1 *= r1;
        float b2 = __builtin_amdgcn_rcpf(1.0f + e1); e1 *= r1;
        float b3 = __builtin_amdgcn_rcpf(1.0f + e1); e1 *= r1;
        float b4 = __builtin_amdgcn_rcpf(1.0f + e1); e1 *= r1;
        float b5 = __builtin_amdgcn_rcpf(1.0f + e1); e1 *= r1;
        float b6 = __builtin_amdgcn_rcpf(1.0f + e1); e1 *= r1;
        float b7 = __builtin_amdgcn_rcpf(1.0f + e1);
        u32x4 p1;
        p1[0] = cvtpk(b0, b1); p1[1] = cvtpk(b2, b3);
        p1[2] = cvtpk(b4, b5); p1[3] = cvtpk(b6, b7);
        *(u32x4*)(bufWr + aw1) = p1;
    };

    f32x4 acc[4][4];
    #pragma unroll
    for (int mi = 0; mi < 4; ++mi)
        #pragma unroll
        for (int ni = 0; ni < 4; ++ni)
            acc[mi][ni] = (f32x4){0.f, 0.f, 0.f, 0.f};

    // ---- prologue: A(0) into As0, B(0) into E register set ----
    f32x2 xv0 = *(const f32x2*)(xptr + 0);
    f32x4 tv0 = *(const f32x4*)(tptr + 0);
    f32x4 tv1 = *(const f32x4*)(tptr + 1);
    stageA(As0, xv0, tv0, tv1);
    short8 bE0 = *(const short8*)(bq0);
    short8 bE1 = *(const short8*)(bq1);
    short8 bE2 = *(const short8*)(bq2);
    short8 bE3 = *(const short8*)(bq3);
    __syncthreads();

    short8 bO0, bO1, bO2, bO3;

    // ---- main loop: 32 double-steps; one __syncthreads per step ----
    #define BODY(T, bufRd, bufWr, bu0, bu1, bu2, bu3, bv0, bv1, bv2, bv3)      \
    {                                                                          \
        const int t_ = (T);                                                    \
        /* A-frag ds_reads for step t */                                       \
        short8 af0 = *(const short8*)((bufRd) + laneA + 0 * 1024);             \
        short8 af1 = *(const short8*)((bufRd) + laneA + 1 * 1024);             \
        short8 af2 = *(const short8*)((bufRd) + laneA + 2 * 1024);             \
        short8 af3 = *(const short8*)((bufRd) + laneA + 3 * 1024);             \
        /* issue B(t+1) into the other register set */                         \
        int kn_ = (t_ + 1 > 63) ? 63 : (t_ + 1);                               \
        int kb_ = kn_ * 64;                                                    \
        int kt_ = kn_ * 8;                                                     \
        bv0 = *(const short8*)(bq0 + kb_);                                     \
        bv1 = *(const short8*)(bq1 + kb_);                                     \
        bv2 = *(const short8*)(bq2 + kb_);                                     \
        bv3 = *(const short8*)(bq3 + kb_);                                     \
        /* x/tab for A(t+1), consumed later this body */                       \
        f32x2 xv_ = *(const f32x2*)(xptr + kt_);                               \
        f32x4 tw0 = *(const f32x4*)(tptr + kt_);                               \
        f32x4 tw1 = *(const f32x4*)(tptr + kt_ + 1);                           \
        /* MFMA: A(t) x B(t) */                                                \
        acc[0][0] = __builtin_amdgcn_mfma_f32_16x16x32_bf16(af0, bu0, acc[0][0], 0, 0, 0); \
        acc[0][1] = __builtin_amdgcn_mfma_f32_16x16x32_bf16(af0, bu1, acc[0][1], 0, 0, 0); \
        acc[0][2] = __builtin_amdgcn_mfma_f32_16x16x32_bf16(af0, bu2, acc[0][2], 0, 0, 0); \
        acc[0][3] = __builtin_amdgcn_mfma_f32_16x16x32_bf16(af0, bu3, acc[0][3], 0, 0, 0); \
        acc[1][0] = __builtin_amdgcn_mfma_f32_16x16x32_bf16(af1, bu0, acc[1][0], 0, 0, 0); \
        acc[1][1] = __builtin_amdgcn_mfma_f32_16x16x32_bf16(af1, bu1, acc[1][1], 0, 0, 0); \
        acc[1][2] = __builtin_amdgcn_mfma_f32_16x16x32_bf16(af1, bu2, acc[1][2], 0, 0, 0); \
        acc[1][3] = __builtin_amdgcn_mfma_f32_16x16x32_bf16(af1, bu3, acc[1][3], 0, 0, 0); \
        acc[2][0] = __builtin_amdgcn_mfma_f32_16x16x32_bf16(af2, bu0, acc[2][0], 0, 0, 0); \
        acc[2][1] = __builtin_amdgcn_mfma_f32_16x16x32_bf16(af2, bu1, acc[2][1], 0, 0, 0); \
        acc[2][2] = __builtin_amdgcn_mfma_f32_16x16x32_bf16(af2, bu2, acc[2][2], 0, 0, 0); \
        acc[2][3] = __builtin_amdgcn_mfma_f32_16x16x32_bf16(af2, bu3, acc[2][3], 0, 0, 0); \
        acc[3][0] = __builtin_amdgcn_mfma_f32_16x16x32_bf16(af3, bu0, acc[3][0], 0, 0, 0); \
        acc[3][1] = __builtin_amdgcn_mfma_f32_16x16x32_bf16(af3, bu1, acc[3][1], 0, 0, 0); \
        acc[3][2] = __builtin_amdgcn_mfma_f32_16x16x32_bf16(af3, bu2, acc[3][2], 0, 0, 0); \
        acc[3][3] = __builtin_amdgcn_mfma_f32_16x16x32_bf16(af3, bu3, acc[3][3], 0, 0, 0); \
        /* build A(t+1) (x/tab arrived under MFMA) */                          \
        stageA((bufWr), xv_, tw0, tw1);                                        \
        __syncthreads();                                                       \
    }

    #pragma unroll 1
    for (int it = 0; it < NSTEPS / 2; ++it) {
        int t = it * 2;
        BODY(t,     As0, As1, bE0, bE1, bE2, bE3, bO0, bO1, bO2, bO3);
        BODY(t + 1, As1, As0, bO0, bO1, bO2, bO3, bE0, bE1, bE2, bE3);
    }
    #undef BODY

    // ---- epilogue: reduce K-halves through LDS, store ----
    if (ks == 1) {
        #pragma unroll
        for (int mi = 0; mi < 4; ++mi)
            #pragma unroll
            for (int ni = 0; ni < 4; ++ni) {
                f32x4 v = acc[mi][ni];
                #pragma unroll
                for (int j = 0; j < 4; ++j) {
                    int row = mi * 16 + fq * 4 + j;
                    int col = wc * 64 + ni * 16 + fr;
                    red[row * BN + col] = v[j];
                }
            }
    }
    __syncthreads();
    if (ks == 0) {
        #pragma unroll
        for (int mi = 0; mi < 4; ++mi)
            #pragma unroll
            for (int ni = 0; ni < 4; ++ni) {
                f32x4 v = acc[mi][ni];
                #pragma unroll
                for (int j = 0; j < 4; ++j) {
                    int row = mi * 16 + fq * 4 + j;
                    int col = wc * 64 + ni * 16 + fr;
                    float s = v[j] + red[row * BN + col];
                    out[(size_t)(bm0 + row) * OUT_F + bn0 + col] = s;
                }
            }
    }
}

// ---------------- launcher ----------------
extern "C" void kernel_launch(void* const* d_in, const int* in_sizes, int n_in,
                              void* d_out, int out_size, void* d_ws, size_t ws_size,
                              hipStream_t stream) {
    const float* x         = (const float*)d_in[0];
    const float* coeffs    = (const float*)d_in[1];
    const float* raw_alpha = (const float*)d_in[2];
    const float* beta      = (const float*)d_in[3];
    const float* centers   = (const float*)d_in[4];
    const float* slopes    = (const float*)d_in[5];
    float* out = (float*)d_out;

    // ws layout: Wb bf16 [OUT_F][KDIM] = 4 MB, then Tab float4[512] = 8 KB
    unsigned short* Wb = (unsigned short*)d_ws;
    float4* Tab = (float4*)((char*)d_ws + (size_t)OUT_F * KDIM * 2);

    prep_tabs<<<dim3((IN_F + 255) / 256), dim3(256), 0, stream>>>(
        raw_alpha, beta, centers, slopes, Tab);

    const int n4 = OUT_F * KDIM / 4;
    prep_wb<<<dim3(n4 / 256), dim3(256), 0, stream>>>(coeffs, Wb, n4);

    fused_tanh_gemm<<<dim3((BATCH / BM) * (OUT_F / BN)), dim3(NTHREADS), 0, stream>>>(
        x, Wb, Tab, out);
}

// Round 9
// 131.997 us; speedup vs baseline: 1.1803x; 1.1803x over previous
//
#include <hip/hip_runtime.h>
#include <hip/hip_bf16.h>
#include <cstdint>
#include <cstddef>

// Problem constants (fixed by setup_inputs)
#define IN_F   512
#define OUT_F  512
#define KBASIS 8
#define BATCH  8192
#define KDIM   (IN_F * KBASIS)   // 4096

// GEMM tiling: 256 blocks (1/CU), 512 threads (8 waves = 4 N-cols x 2 K-halves)
#define BM 64
#define BN 256
#define NSTEPS 64                 // 64 kdim (8 features) per step
#define NTHREADS 512

typedef __attribute__((ext_vector_type(8))) short  short8;   // bf16x8 MFMA frag
typedef __attribute__((ext_vector_type(4))) float  f32x4;
typedef __attribute__((ext_vector_type(4))) unsigned int u32x4;

static __device__ __forceinline__ unsigned short f2bf16(float f) {
    union { float f; unsigned u; } v; v.f = f;
    unsigned u = v.u;
    return (unsigned short)((u + 0x7FFFu + ((u >> 16) & 1u)) >> 16);  // RNE
}

static __device__ __forceinline__ unsigned cvtpk(float lo, float hi) {
    unsigned r;
    asm("v_cvt_pk_bf16_f32 %0, %1, %2" : "=v"(r) : "v"(lo), "v"(hi));
    return r;
}

// ---------------- prep 1: per-feature table, interleaved float4 ----------
// basis_{i,k}(x) = rcp(1 + e_k), e_k = exp2(KA_i*x + KB0_i) * RR_i^k
__global__ void prep_tabs(const float* __restrict__ raw_alpha,
                          const float* __restrict__ beta,
                          const float* __restrict__ centers,
                          const float* __restrict__ slopes,
                          float4* __restrict__ Tab) {
    int i = blockIdx.x * blockDim.x + threadIdx.x;
    if (i >= IN_F) return;
    float ra = raw_alpha[i];
    float sp = (ra > 20.f) ? ra : log1pf(expf(ra));   // softplus
    float alpha = sp + 1e-6f;
    const float NEG2LOG2E = -2.8853900817779268f;     // -2*log2(e)
    float s0 = slopes[i * KBASIS + 0], c0 = centers[i * KBASIS + 0];
    float s1 = slopes[i * KBASIS + 1], c1 = centers[i * KBASIS + 1];
    float kb0 = NEG2LOG2E * s0 * (beta[i] - c0);
    float kb1 = NEG2LOG2E * s1 * (beta[i] - c1);
    float4 t;
    t.x = NEG2LOG2E * s0 * alpha;   // KA
    t.y = kb0;                      // KB0
    t.z = exp2f(kb1 - kb0);         // RR
    t.w = 0.f;
    Tab[i] = t;
}

// ---------------- prep 2: coeffs fp32 -> bf16, TRANSPOSED chunk-major ------
// Wb2[chunk][o][8] where chunk = k/8: B-frag loads become 256B-contiguous.
__global__ void prep_wbt(const float* __restrict__ w,
                         unsigned short* __restrict__ wb2) {
    int tid = blockIdx.x * blockDim.x + threadIdx.x;   // 262144 threads
    int chunk = tid >> 9;          // 0..511
    int o     = tid & 511;         // 0..511
    const float* src = w + (size_t)o * KDIM + chunk * 8;
    float4 v0 = *(const float4*)src;
    float4 v1 = *(const float4*)(src + 4);
    union { ushort4 u4[2]; unsigned short us[8]; } r;
    r.us[0] = f2bf16(v0.x); r.us[1] = f2bf16(v0.y);
    r.us[2] = f2bf16(v0.z); r.us[3] = f2bf16(v0.w);
    r.us[4] = f2bf16(v1.x); r.us[5] = f2bf16(v1.y);
    r.us[6] = f2bf16(v1.z); r.us[7] = f2bf16(v1.w);
    *(u32x4*)(wb2 + (size_t)chunk * OUT_F * 8 + o * 8) = *(u32x4*)&r;
}

// ---------------- fused basis-expansion GEMM ----------------
// B-frags global->reg, E/O register double-buffer (compiler-tracked vmcnt).
// A staged via 16 KB LDS double buffer; tables in LDS (8 KB).
// Barrier = lgkmcnt(0)-only + raw s_barrier: VMEM floats across steps.
__global__ __launch_bounds__(NTHREADS, 2)
void fused_tanh_gemm(const float* __restrict__ x,
                     const unsigned short* __restrict__ Wb,   // transposed bf16
                     const float4* __restrict__ Tab,
                     float* __restrict__ out) {
    __shared__ __align__(16) char smem[64 * 1024];
    unsigned short* As0 = (unsigned short*)smem;          // [64][64] bf16, 8 KB
    unsigned short* As1 = As0 + 64 * 64;
    float* ldsTab = (float*)(smem + 16384);               // 512 x float4 = 8 KB
    float* red    = (float*)smem;                         // epilogue alias 64 KB

    const int tid  = threadIdx.x;
    const int wid  = tid >> 6;
    const int lane = tid & 63;

    // XCD mapping (R4-proven): each XCD pins one 2MB Wb half in its L2
    const int bid = blockIdx.x;            // 256 blocks
    const int xcd = bid & 7;
    const int rix = bid >> 3;              // 0..31
    const int bn0 = (xcd & 1) * BN;
    const int bm0 = ((xcd >> 1) * 32 + rix) * BM;

    // wave roles
    const int wc = wid & 3;                // N column 0..3
    const int ks = wid >> 2;               // K half 0..1
    const int fr = lane & 15;
    const int fq = lane >> 4;              // 0..3

    // A staging coords: one feature-chunk (8 basis vals) per thread
    const int arow = tid >> 3;             // 0..63
    const int ac   = tid & 7;              // feature-chunk 0..7
    const float* xptr0 = x + (size_t)(bm0 + arow) * IN_F;

    const int aw0   = arow * 64 + (ac ^ (arow & 7)) * 8;        // A-write (elems)
    const int sidx  = (ks * 4 + fq) ^ (fr & 7);
    const int laneA = fr * 64 + sidx * 8;                       // A-read (elems)

    // B base (transposed layout): chunk = ks*4+fq (+ t*8), col = bn0+wc*64+ni*16+fr
    const unsigned short* bqb =
        Wb + ((size_t)(ks * 4 + fq) * OUT_F + bn0 + wc * 64 + fr) * 8;
    // per-frag: +ni*16 cols = +ni*128 elems; per-step: +8 chunks = +32768 elems

    auto stageA = [&](unsigned short* bufWr, float xv, f32x4 tb) {
        float e = __builtin_amdgcn_exp2f(tb[0] * xv + tb[1]);
        float rr = tb[2];
        float s0 = __builtin_amdgcn_rcpf(1.0f + e); e *= rr;
        float s1 = __builtin_amdgcn_rcpf(1.0f + e); e *= rr;
        float s2 = __builtin_amdgcn_rcpf(1.0f + e); e *= rr;
        float s3 = __builtin_amdgcn_rcpf(1.0f + e); e *= rr;
        float s4 = __builtin_amdgcn_rcpf(1.0f + e); e *= rr;
        float s5 = __builtin_amdgcn_rcpf(1.0f + e); e *= rr;
        float s6 = __builtin_amdgcn_rcpf(1.0f + e); e *= rr;
        float s7 = __builtin_amdgcn_rcpf(1.0f + e);
        u32x4 pk;
        pk[0] = cvtpk(s0, s1); pk[1] = cvtpk(s2, s3);
        pk[2] = cvtpk(s4, s5); pk[3] = cvtpk(s6, s7);
        *(u32x4*)(bufWr + aw0) = pk;                  // one ds_write_b128
    };

    f32x4 acc[4][4];
    #pragma unroll
    for (int mi = 0; mi < 4; ++mi)
        #pragma unroll
        for (int ni = 0; ni < 4; ++ni)
            acc[mi][ni] = (f32x4){0.f, 0.f, 0.f, 0.f};

    // ---- prologue ----
    *(float4*)(ldsTab + tid * 4) = Tab[tid];          // tables -> LDS
    __syncthreads();                                  // full fence once (tab visible)
    {
        f32x4 tb = *(const f32x4*)(ldsTab + ac * 4);  // A(0): ai = ac
        float xv = xptr0[ac];
        stageA(As0, xv, tb);
    }
    short8 bE0 = *(const short8*)(bqb + 0 * 128);     // B(0) -> E set
    short8 bE1 = *(const short8*)(bqb + 1 * 128);
    short8 bE2 = *(const short8*)(bqb + 2 * 128);
    short8 bE3 = *(const short8*)(bqb + 3 * 128);
    asm volatile("s_waitcnt lgkmcnt(0)" ::: "memory");
    __builtin_amdgcn_sched_barrier(0);
    __builtin_amdgcn_s_barrier();
    __builtin_amdgcn_sched_barrier(0);

    short8 bO0, bO1, bO2, bO3;

    // ---- main loop: one LDS-only barrier per K-step; VMEM floats across ----
    #define BODY(T, bufRd, bufWr, bu0, bu1, bu2, bu3, bv0, bv1, bv2, bv3)      \
    {                                                                          \
        const int t_ = (T);                                                    \
        /* A-frag ds_reads for step t (critical path to MFMA) */               \
        short8 af0 = *(const short8*)((bufRd) + laneA + 0 * 1024);             \
        short8 af1 = *(const short8*)((bufRd) + laneA + 1 * 1024);             \
        short8 af2 = *(const short8*)((bufRd) + laneA + 2 * 1024);             \
        short8 af3 = *(const short8*)((bufRd) + laneA + 3 * 1024);             \
        /* prefetch issues: B(t+1) -> other reg set; x/tab(t+1) for stageA */  \
        const int kn_ = (t_ + 1 > 63) ? 63 : (t_ + 1);                         \
        f32x4 tb_ = *(const f32x4*)(ldsTab + (kn_ * 8 + ac) * 4);              \
        float xv_ = xptr0[kn_ * 8 + ac];                                       \
        const unsigned short* bp_ = bqb + (size_t)kn_ * 32768;                 \
        bv0 = *(const short8*)(bp_ + 0 * 128);                                 \
        bv1 = *(const short8*)(bp_ + 1 * 128);                                 \
        bv2 = *(const short8*)(bp_ + 2 * 128);                                 \
        bv3 = *(const short8*)(bp_ + 3 * 128);                                 \
        __builtin_amdgcn_sched_barrier(0);  /* pin issues above MFMA */        \
        /* MFMA: A(t) x B(t) (compiler waits af/bu deps) */                    \
        __builtin_amdgcn_s_setprio(1);                                         \
        acc[0][0] = __builtin_amdgcn_mfma_f32_16x16x32_bf16(af0, bu0, acc[0][0], 0, 0, 0); \
        acc[0][1] = __builtin_amdgcn_mfma_f32_16x16x32_bf16(af0, bu1, acc[0][1], 0, 0, 0); \
        acc[0][2] = __builtin_amdgcn_mfma_f32_16x16x32_bf16(af0, bu2, acc[0][2], 0, 0, 0); \
        acc[0][3] = __builtin_amdgcn_mfma_f32_16x16x32_bf16(af0, bu3, acc[0][3], 0, 0, 0); \
        acc[1][0] = __builtin_amdgcn_mfma_f32_16x16x32_bf16(af1, bu0, acc[1][0], 0, 0, 0); \
        acc[1][1] = __builtin_amdgcn_mfma_f32_16x16x32_bf16(af1, bu1, acc[1][1], 0, 0, 0); \
        acc[1][2] = __builtin_amdgcn_mfma_f32_16x16x32_bf16(af1, bu2, acc[1][2], 0, 0, 0); \
        acc[1][3] = __builtin_amdgcn_mfma_f32_16x16x32_bf16(af1, bu3, acc[1][3], 0, 0, 0); \
        acc[2][0] = __builtin_amdgcn_mfma_f32_16x16x32_bf16(af2, bu0, acc[2][0], 0, 0, 0); \
        acc[2][1] = __builtin_amdgcn_mfma_f32_16x16x32_bf16(af2, bu1, acc[2][1], 0, 0, 0); \
        acc[2][2] = __builtin_amdgcn_mfma_f32_16x16x32_bf16(af2, bu2, acc[2][2], 0, 0, 0); \
        acc[2][3] = __builtin_amdgcn_mfma_f32_16x16x32_bf16(af2, bu3, acc[2][3], 0, 0, 0); \
        acc[3][0] = __builtin_amdgcn_mfma_f32_16x16x32_bf16(af3, bu0, acc[3][0], 0, 0, 0); \
        acc[3][1] = __builtin_amdgcn_mfma_f32_16x16x32_bf16(af3, bu1, acc[3][1], 0, 0, 0); \
        acc[3][2] = __builtin_amdgcn_mfma_f32_16x16x32_bf16(af3, bu2, acc[3][2], 0, 0, 0); \
        acc[3][3] = __builtin_amdgcn_mfma_f32_16x16x32_bf16(af3, bu3, acc[3][3], 0, 0, 0); \
        __builtin_amdgcn_s_setprio(0);                                         \
        /* build A(t+1): x/tab latency hidden under MFMA above */              \
        stageA((bufWr), xv_, tb_);                                             \
        /* LDS-only fence: A-writes/reads drained; VMEM stays in flight */     \
        asm volatile("s_waitcnt lgkmcnt(0)" ::: "memory");                     \
        __builtin_amdgcn_sched_barrier(0);                                     \
        __builtin_amdgcn_s_barrier();                                          \
        __builtin_amdgcn_sched_barrier(0);                                     \
    }

    #pragma unroll 1
    for (int it = 0; it < NSTEPS / 2; ++it) {
        int t = it * 2;
        BODY(t,     As0, As1, bE0, bE1, bE2, bE3, bO0, bO1, bO2, bO3);
        BODY(t + 1, As1, As0, bO0, bO1, bO2, bO3, bE0, bE1, bE2, bE3);
    }
    #undef BODY

    // ---- epilogue: reduce K-halves through LDS, store ----
    __syncthreads();
    if (ks == 1) {
        #pragma unroll
        for (int mi = 0; mi < 4; ++mi)
            #pragma unroll
            for (int ni = 0; ni < 4; ++ni) {
                f32x4 v = acc[mi][ni];
                #pragma unroll
                for (int j = 0; j < 4; ++j) {
                    int row = mi * 16 + fq * 4 + j;
                    int col = ni * 16 + fr;
                    red[(wc * 64 + row) * 64 + col] = v[j];
                }
            }
    }
    __syncthreads();
    if (ks == 0) {
        #pragma unroll
        for (int mi = 0; mi < 4; ++mi)
            #pragma unroll
            for (int ni = 0; ni < 4; ++ni) {
                f32x4 v = acc[mi][ni];
                #pragma unroll
                for (int j = 0; j < 4; ++j) {
                    int row = mi * 16 + fq * 4 + j;
                    int col = ni * 16 + fr;
                    float s = v[j] + red[(wc * 64 + row) * 64 + col];
                    out[(size_t)(bm0 + row) * OUT_F + bn0 + wc * 64 + col] = s;
                }
            }
    }
}

// ---------------- launcher ----------------
extern "C" void kernel_launch(void* const* d_in, const int* in_sizes, int n_in,
                              void* d_out, int out_size, void* d_ws, size_t ws_size,
                              hipStream_t stream) {
    const float* x         = (const float*)d_in[0];
    const float* coeffs    = (const float*)d_in[1];
    const float* raw_alpha = (const float*)d_in[2];
    const float* beta      = (const float*)d_in[3];
    const float* centers   = (const float*)d_in[4];
    const float* slopes    = (const float*)d_in[5];
    float* out = (float*)d_out;

    // ws layout: Wb2 bf16 transposed [512][512][8] = 4 MB, then Tab = 8 KB
    unsigned short* Wb2 = (unsigned short*)d_ws;
    float4* Tab = (float4*)((char*)d_ws + (size_t)OUT_F * KDIM * 2);

    prep_tabs<<<dim3((IN_F + 255) / 256), dim3(256), 0, stream>>>(
        raw_alpha, beta, centers, slopes, Tab);

    prep_wbt<<<dim3(262144 / 256), dim3(256), 0, stream>>>(coeffs, Wb2);

    fused_tanh_gemm<<<dim3(256), dim3(NTHREADS), 0, stream>>>(
        x, Wb2, Tab, out);
}